// Round 4
// baseline (535.661 us; speedup 1.0000x reference)
//
#include <hip/hip_runtime.h>

// Subtractor50Bit: A - B via two's complement, N rows x 50 bits ({0,1} floats).
// out = [result (N*50 floats), borrow (N floats)].
//
// R5: maximum-TLP streaming rewrite.
// R0-R4 post-mortem: four structurally different kernels (ballot-transpose
// register-staged x3, LDS-staged async x1) ALL plateau at 2.3-2.7 TB/s /
// ~151-173us with nothing saturated. Unified model: every one had
// burst-drain structure -- loads in flight only ~10-20% of wave lifetime,
// so sustained bytes-in-flight/CU ~= 8-12KB, exactly predicting 2.3-2.7
// TB/s at ~900cy latency. LN-style plain grid-stride streaming hits 82%
// HBM on this chip (guide m219), so the fix is that structure:
//   - one thread = 2 consecutive rows (400B, float4-aligned; single rows
//     are only 8B-aligned)
//   - 50 rolling float4 loads/thread, pack via bit23 extract, 64-bit
//     subtract, unpack, 25 float4 stores + float2 borrow
//   - NO LDS, NO ballots, NO shuffles, NO barriers, NO vmcnt drains.
//   - ~30 waves/CU x rolling window -> sustained in-flight far above the
//     ~9KB/CU needed for full BW; loads/stores continuously interleaved.
// Wave footprint (2x 25.6KB) streams through L1; every fetched byte used.

constexpr int BITS = 50;
constexpr unsigned long long MASK50 = (1ULL << BITS) - 1ULL;

// Accumulate bit for flat element e (0..99) of a row-pair into the
// per-row 50-bit accumulators. e is compile-time constant after unroll.
__device__ __forceinline__ void accbit(unsigned bit, int e,
    unsigned& lo0, unsigned& hi0, unsigned& lo1, unsigned& hi1)
{
    if (e < 32)      lo0 |= bit << e;
    else if (e < 50) hi0 |= bit << (e - 32);
    else if (e < 82) lo1 |= bit << (e - 50);
    else             hi1 |= bit << (e - 82);
}

// Result bit for flat element e (0..99) of the row-pair, as 0.0f/1.0f.
__device__ __forceinline__ float dbit(unsigned long long d0,
                                      unsigned long long d1, int e)
{
    unsigned long long d = (e < 50) ? d0 : d1;
    int k = (e < 50) ? e : e - 50;
    return (float)((unsigned)(d >> k) & 1u);
}

__global__ __launch_bounds__(256) void Subtractor50Bit_kernel(
    const float* __restrict__ A, const float* __restrict__ B,
    float* __restrict__ out, int N)
{
    const long long t  = (long long)blockIdx.x * 256 + threadIdx.x;
    const long long r0 = 2 * t;                 // first row of this thread's pair
    if (r0 >= N) return;

    if (r0 + 2 <= N) {
        // ---- fast path: two full rows = 400B, 16B-aligned ----
        const float4* pa = (const float4*)(A + r0 * BITS);
        const float4* pb = (const float4*)(B + r0 * BITS);

        unsigned alo0 = 0, ahi0 = 0, alo1 = 0, ahi1 = 0;
        unsigned blo0 = 0, bhi0 = 0, blo1 = 0, bhi1 = 0;

        #pragma unroll
        for (int j = 0; j < 25; ++j) {
            float4 va = pa[j];
            float4 vb = pb[j];
            accbit((__float_as_uint(va.x) >> 23) & 1u, 4*j+0, alo0, ahi0, alo1, ahi1);
            accbit((__float_as_uint(va.y) >> 23) & 1u, 4*j+1, alo0, ahi0, alo1, ahi1);
            accbit((__float_as_uint(va.z) >> 23) & 1u, 4*j+2, alo0, ahi0, alo1, ahi1);
            accbit((__float_as_uint(va.w) >> 23) & 1u, 4*j+3, alo0, ahi0, alo1, ahi1);
            accbit((__float_as_uint(vb.x) >> 23) & 1u, 4*j+0, blo0, bhi0, blo1, bhi1);
            accbit((__float_as_uint(vb.y) >> 23) & 1u, 4*j+1, blo0, bhi0, blo1, bhi1);
            accbit((__float_as_uint(vb.z) >> 23) & 1u, 4*j+2, blo0, bhi0, blo1, bhi1);
            accbit((__float_as_uint(vb.w) >> 23) & 1u, 4*j+3, blo0, bhi0, blo1, bhi1);
        }

        const unsigned long long av0 = alo0 | ((unsigned long long)ahi0 << 32);
        const unsigned long long bv0 = blo0 | ((unsigned long long)bhi0 << 32);
        const unsigned long long av1 = alo1 | ((unsigned long long)ahi1 << 32);
        const unsigned long long bv1 = blo1 | ((unsigned long long)bhi1 << 32);

        const unsigned long long d0 = (av0 - bv0) & MASK50;  // A + ~B + 1 (mod 2^50)
        const unsigned long long d1 = (av1 - bv1) & MASK50;
        const float bw0 = (av0 < bv0) ? 1.0f : 0.0f;         // 1 - carry_out
        const float bw1 = (av1 < bv1) ? 1.0f : 0.0f;

        float4* po = (float4*)(out + r0 * BITS);
        #pragma unroll
        for (int j = 0; j < 25; ++j) {
            float4 o;
            o.x = dbit(d0, d1, 4*j+0);
            o.y = dbit(d0, d1, 4*j+1);
            o.z = dbit(d0, d1, 4*j+2);
            o.w = dbit(d0, d1, 4*j+3);
            po[j] = o;
        }

        float2 bo;
        bo.x = bw0;
        bo.y = bw1;
        *(float2*)(out + (long long)N * BITS + r0) = bo;     // 8B-aligned (r0 even)
    } else {
        // ---- single trailing row (odd N safety net) ----
        const long long r = r0;
        unsigned long long av = 0, bv = 0;
        for (int k = 0; k < BITS; ++k) {
            av |= (unsigned long long)(A[r * BITS + k] != 0.0f) << k;
            bv |= (unsigned long long)(B[r * BITS + k] != 0.0f) << k;
        }
        const unsigned long long diff = (av - bv) & MASK50;
        for (int k = 0; k < BITS; ++k)
            out[r * BITS + k] = (float)((diff >> k) & 1ULL);
        out[(long long)N * BITS + r] = (av < bv) ? 1.0f : 0.0f;
    }
}

extern "C" void kernel_launch(void* const* d_in, const int* in_sizes, int n_in,
                              void* d_out, int out_size, void* d_ws, size_t ws_size,
                              hipStream_t stream) {
    const float* A = (const float*)d_in[0];
    const float* B = (const float*)d_in[1];
    float* out = (float*)d_out;
    const int N = in_sizes[0] / BITS;           // 1,000,000

    const long long pairs  = ((long long)N + 1) / 2;   // one thread per 2 rows
    const int       blocks = (int)((pairs + 255) / 256);
    Subtractor50Bit_kernel<<<blocks, 256, 0, stream>>>(A, B, out, N);
}

// Round 5
// 450.105 us; speedup vs baseline: 1.1901x; 1.1901x over previous
//
#include <hip/hip_runtime.h>

// Subtractor50Bit: A - B via two's complement, N rows x 50 bits ({0,1} floats).
// out = [result (N*50 floats), borrow (N floats)].
//
// R6: R4's LDS-staged structure + T3/T4-style double-buffered pipeline.
// R0-R5 unified post-mortem: every kernel was burst-drain (loads in flight
// 10-20% of wave lifetime -> 8-12KB/CU sustained -> 2.4-2.7 TB/s at ~900cy,
// matching ALL five measurements). R4 drained vmcnt(0) then computed ~2-3K
// cycles with zero bytes in flight. Fix (GEMM-ladder T3/T4): persistent
// 1-wave blocks grid-striding over tiles, double-buffered LDS; each
// iteration issues the NEXT tile's 28 async global_load_lds ops first,
// then waits vmcnt(28) -- current buffer ready, next tile's 25.6KB stays
// in flight across the whole compute+store phase. 3 blocks/CU (51.2KB LDS)
// -> ~77KB/CU continuously in flight, ~8x the full-BW requirement.
// Low occupancy (3 waves/CU) is EXPECTED; loads no longer depend on it.

constexpr int BITS = 50;
constexpr unsigned long long MASK50 = (1ULL << BITS) - 1ULL;
constexpr int TILE_F = 3200;              // 64 rows x 50 floats

// HBM -> LDS direct copy. LDS dest = wave-uniform base + lane*size.
__device__ __forceinline__ void gl_lds16(const float* g, float* l) {
    __builtin_amdgcn_global_load_lds(
        (const __attribute__((address_space(1))) void*)g,
        (__attribute__((address_space(3))) void*)l, 16, 0, 0);
}
__device__ __forceinline__ void gl_lds4(const float* g, float* l) {
    __builtin_amdgcn_global_load_lds(
        (const __attribute__((address_space(1))) void*)g,
        (__attribute__((address_space(3))) void*)l, 4, 0, 0);
}

// 14 VMEM ops per operand tile (12 x 1KB + 2 x 256B), 28 per call.
__device__ __forceinline__ void stage_tile(const float* ga, const float* gb,
                                           float* la, float* lb, int lane) {
    #pragma unroll
    for (int j = 0; j < 12; ++j) gl_lds16(ga + 256 * j + 4 * lane, la + 256 * j);
    gl_lds4(ga + 3072 + lane, la + 3072);
    gl_lds4(ga + 3136 + lane, la + 3136);
    #pragma unroll
    for (int j = 0; j < 12; ++j) gl_lds16(gb + 256 * j + 4 * lane, lb + 256 * j);
    gl_lds4(gb + 3072 + lane, lb + 3072);
    gl_lds4(gb + 3136 + lane, lb + 3136);
}

__global__ __launch_bounds__(64) void Subtractor50Bit_kernel(
    const float* __restrict__ A, const float* __restrict__ B,
    float* __restrict__ out, int N)
{
    __shared__ float sA[2][TILE_F];   // 2 x 12.8 KB  (result reuses sA[par])
    __shared__ float sB[2][TILE_F];   // 2 x 12.8 KB  -> 51.2 KB total

    const int lane = threadIdx.x;             // 64-thread block = 1 wave
    const long long nFull = (long long)N >> 6; // full 64-row tiles
    const long long step  = gridDim.x;

    long long t = blockIdx.x;
    int par = 0;

    if (t < nFull) {
        stage_tile(A + t * TILE_F, B + t * TILE_F, sA[0], sB[0], lane);
    }

    for (; t < nFull; t += step, par ^= 1) {
        const long long tn = t + step;

        // ---- issue NEXT tile's loads first; wait only for CURRENT buffer.
        if (tn < nFull) {
            __builtin_amdgcn_sched_barrier(0);
            stage_tile(A + tn * TILE_F, B + tn * TILE_F,
                       sA[par ^ 1], sB[par ^ 1], lane);
            __builtin_amdgcn_sched_barrier(0);
            // 28 newest outstanding VMEM ops = the tn-stage; everything
            // older (tile t's loads, prior stores) must complete.
            asm volatile("s_waitcnt vmcnt(28)" ::: "memory");
        } else {
            __builtin_amdgcn_sched_barrier(0);
            asm volatile("s_waitcnt vmcnt(0)" ::: "memory");
        }
        __builtin_amdgcn_sched_barrier(0);

        // ---- Phase 2: lane owns row (64t+lane); read 50 floats from LDS,
        // pack to 50-bit int via exponent bit23 (inputs are exact {0,1}).
        const float2* rA = (const float2*)sA[par] + 25 * lane;
        const float2* rB = (const float2*)sB[par] + 25 * lane;
        unsigned alo = 0, ahi = 0, blo = 0, bhi = 0;
        #pragma unroll
        for (int j = 0; j < 25; ++j) {
            float2 va = rA[j];
            float2 vb = rB[j];
            unsigned a0 = (__float_as_uint(va.x) >> 23) & 1u;
            unsigned a1 = (__float_as_uint(va.y) >> 23) & 1u;
            unsigned b0 = (__float_as_uint(vb.x) >> 23) & 1u;
            unsigned b1 = (__float_as_uint(vb.y) >> 23) & 1u;
            if (j < 16) {
                alo |= a0 << (2 * j); alo |= a1 << (2 * j + 1);
                blo |= b0 << (2 * j); blo |= b1 << (2 * j + 1);
            } else {
                ahi |= a0 << (2 * j - 32); ahi |= a1 << (2 * j - 31);
                bhi |= b0 << (2 * j - 32); bhi |= b1 << (2 * j - 31);
            }
        }
        unsigned long long av = ((unsigned long long)ahi << 32) | alo;
        unsigned long long bv = ((unsigned long long)bhi << 32) | blo;

        unsigned long long diff = (av - bv) & MASK50;  // A + ~B + 1 (mod 2^50)
        float borrow = (av < bv) ? 1.0f : 0.0f;        // 1 - carry_out

        // ---- Phase 3: unpack result bits, row back into sA[par].
        float2* wO = (float2*)sA[par] + 25 * lane;
        #pragma unroll
        for (int j = 0; j < 25; ++j) {
            float2 o;
            o.x = (float)(unsigned)((diff >> (2 * j)) & 1ULL);
            o.y = (float)(unsigned)((diff >> (2 * j + 1)) & 1ULL);
            wO[j] = o;
        }

        // ---- Phase 4: coalesced wide stores straight from LDS.
        // (Single wave per block: program order + lgkmcnt orders the
        // cross-lane LDS reads after phase-3 writes; no barrier needed.)
        const long long eBase = t * TILE_F;
        const float4* sO4 = (const float4*)sA[par];
        float4* go4 = (float4*)(out + eBase);
        #pragma unroll
        for (int j = 0; j < 12; ++j) go4[64 * j + lane] = sO4[64 * j + lane];
        const float2* sO2 = (const float2*)(sA[par] + 3072);
        float2* go2 = (float2*)(out + eBase + 3072);
        go2[lane] = sO2[lane];

        // borrow segment: naturally coalesced
        out[(long long)N * BITS + t * 64 + lane] = borrow;
    }

    // ---- remainder rows (N % 64 != 0 safety net): block 0, lane-per-row.
    if (blockIdx.x == 0) {
        long long r = nFull * 64 + lane;
        if (r < N) {
            unsigned long long av = 0, bv = 0;
            for (int k = 0; k < BITS; ++k) {
                av |= (unsigned long long)(A[r * BITS + k] != 0.0f) << k;
                bv |= (unsigned long long)(B[r * BITS + k] != 0.0f) << k;
            }
            unsigned long long diff = (av - bv) & MASK50;
            for (int k = 0; k < BITS; ++k)
                out[r * BITS + k] = (float)((diff >> k) & 1ULL);
            out[(long long)N * BITS + r] = (av < bv) ? 1.0f : 0.0f;
        }
    }
}

extern "C" void kernel_launch(void* const* d_in, const int* in_sizes, int n_in,
                              void* d_out, int out_size, void* d_ws, size_t ws_size,
                              hipStream_t stream) {
    const float* A = (const float*)d_in[0];
    const float* B = (const float*)d_in[1];
    float* out = (float*)d_out;
    const int N = in_sizes[0] / BITS;          // 1,000,000

    const long long nFull = (long long)N >> 6;
    // 3 blocks/CU (51.2 KB LDS each) x 256 CUs = 768 persistent blocks.
    long long want = nFull < 768 ? (nFull > 0 ? nFull : 1) : 768;
    Subtractor50Bit_kernel<<<(int)want, 64, 0, stream>>>(A, B, out, N);
}